// Round 2
// baseline (3307.492 us; speedup 1.0000x reference)
//
#include <hip/hip_runtime.h>

static constexpr int NSIDE = 48;
static constexpr int NVOX  = NSIDE * NSIDE * NSIDE;   // 110592
static constexpr float SCALE = 0.041875863808787856f; // ONE_OVER_DIFF_TOT * DIFF_Q

// Neighbor offsets = -SHIFTS (jnp.roll(q, s) => nb[p] = q[p - s]).
// Order matches D_INV: 6 faces (1), 12 edges (1/sqrt2), 8 corners (1/sqrt3).
__device__ __constant__ int c_ox[26] = { 1,-1, 0, 0, 0, 0,
                                         1,-1, 1,-1, 1,-1, 1,-1, 0, 0, 0, 0,
                                         1, 1, 1, 1,-1,-1,-1,-1 };
__device__ __constant__ int c_oy[26] = { 0, 0, 1,-1, 0, 0,
                                         1, 1,-1,-1, 0, 0, 0, 0, 1,-1, 1,-1,
                                         1, 1,-1,-1, 1, 1,-1,-1 };
__device__ __constant__ int c_oz[26] = { 0, 0, 0, 0, 1,-1,
                                         0, 0, 0, 0, 1, 1,-1,-1, 1, 1,-1,-1,
                                         1,-1, 1,-1, 1,-1, 1,-1 };
__device__ __constant__ float c_dinv[26] = {
    1.f, 1.f, 1.f, 1.f, 1.f, 1.f,
    0.70710678118654752f, 0.70710678118654752f, 0.70710678118654752f, 0.70710678118654752f,
    0.70710678118654752f, 0.70710678118654752f, 0.70710678118654752f, 0.70710678118654752f,
    0.70710678118654752f, 0.70710678118654752f, 0.70710678118654752f, 0.70710678118654752f,
    0.57735026918962576f, 0.57735026918962576f, 0.57735026918962576f, 0.57735026918962576f,
    0.57735026918962576f, 0.57735026918962576f, 0.57735026918962576f, 0.57735026918962576f };

__device__ __forceinline__ float fast_tanh(float x) {
    // tanh(x) = 1 - 2/(exp2(2*log2e*x)+1); exact saturation at +-inf.
    float e = __builtin_amdgcn_exp2f(x * 2.8853900817779268f);
    float r = __builtin_amdgcn_rcpf(e + 1.0f);
    return fmaf(-2.0f, r, 1.0f);
}

// LDS weight layout (floats):
//  W0:[0,64) b0:[64,80) W1:[80,336) b1:[336,352) W2:[352,608) b2:[608,624)
//  W3:[624,880) b3:[880,896) Wout:[896,912) bout:[912]
__global__ __launch_bounds__(256, 4)   // cap VGPRs at 128: true need ~90, stops spill
void automaton_kernel(const float* __restrict__ q,
                      const float* __restrict__ W0, const float* __restrict__ b0,
                      const float* __restrict__ W1, const float* __restrict__ b1,
                      const float* __restrict__ W2, const float* __restrict__ b2,
                      const float* __restrict__ W3, const float* __restrict__ b3,
                      const float* __restrict__ Wout, const float* __restrict__ bout,
                      float* __restrict__ out)
{
    __shared__ __align__(16) float sw[916];
    const int t = threadIdx.x;
    if (t <  64) sw[      t] = W0[t];
    if (t <  16) sw[ 64 + t] = b0[t];
                 sw[ 80 + t] = W1[t];
    if (t <  16) sw[336 + t] = b1[t];
                 sw[352 + t] = W2[t];
    if (t <  16) sw[608 + t] = b2[t];
                 sw[624 + t] = W3[t];
    if (t <  16) sw[880 + t] = b3[t];
    if (t <  16) sw[896 + t] = Wout[t];
    if (t ==  0) sw[912]     = bout[0];
    __syncthreads();

    const int gid  = blockIdx.x * 256 + t;          // 0 .. 221183
    const int vox  = gid >> 1;
    const int half = gid & 1;

    const int z = vox % NSIDE;
    const int y = (vox / NSIDE) % NSIDE;
    const int x = vox / (NSIDE * NSIDE);
    const int xm = (x == 0) ? NSIDE - 1 : x - 1;
    const int xp = (x == NSIDE - 1) ? 0 : x + 1;
    const int ym = (y == 0) ? NSIDE - 1 : y - 1;
    const int yp = (y == NSIDE - 1) ? 0 : y + 1;
    const int zm = (z == 0) ? NSIDE - 1 : z - 1;
    const int zp = (z == NSIDE - 1) ? 0 : z + 1;

    const float2 own = reinterpret_cast<const float2*>(q)[vox];
    const float o0 = own.x, o1 = own.y;

    float ha[16], hb[16], ta[16], tb[16];

// one 16->16 tanh layer on both evals, weights shared per load
#define LAYER(WB, INA, INB, OUTA, OUTB)                                        \
    {                                                                          \
        _Pragma("unroll")                                                      \
        for (int i = 0; i < 16; ++i) {                                         \
            float aa = sw[(WB) + 256 + i];                                     \
            float ab = aa;                                                     \
            _Pragma("unroll")                                                  \
            for (int kk = 0; kk < 4; ++kk) {                                   \
                const float4 w = *reinterpret_cast<const float4*>(             \
                    &sw[(WB) + i * 16 + kk * 4]);                              \
                aa = fmaf(w.x, INA[4 * kk + 0], aa);                           \
                aa = fmaf(w.y, INA[4 * kk + 1], aa);                           \
                aa = fmaf(w.z, INA[4 * kk + 2], aa);                           \
                aa = fmaf(w.w, INA[4 * kk + 3], aa);                           \
                ab = fmaf(w.x, INB[4 * kk + 0], ab);                           \
                ab = fmaf(w.y, INB[4 * kk + 1], ab);                           \
                ab = fmaf(w.z, INB[4 * kk + 2], ab);                           \
                ab = fmaf(w.w, INB[4 * kk + 3], ab);                           \
            }                                                                  \
            OUTA[i] = fast_tanh(aa);                                           \
            OUTB[i] = fast_tanh(ab);                                           \
        }                                                                      \
    }

    float sum = 0.0f;
    #pragma unroll 1
    for (int k = half * 13; k < half * 13 + 13; ++k) {
        const int ox = c_ox[k], oy = c_oy[k], oz = c_oz[k];
        const int nx = (ox < 0) ? xm : ((ox > 0) ? xp : x);
        const int ny = (oy < 0) ? ym : ((oy > 0) ? yp : y);
        const int nz = (oz < 0) ? zm : ((oz > 0) ? zp : z);
        const float2 nbq = reinterpret_cast<const float2*>(q)[(nx * NSIDE + ny) * NSIDE + nz];
        const float n0 = nbq.x, n1 = nbq.y;

        // layer 0: 4 -> 16, both orderings share the weight load
        #pragma unroll
        for (int i = 0; i < 16; ++i) {
            const float4 w = *reinterpret_cast<const float4*>(&sw[i * 4]);
            const float bb = sw[64 + i];
            float pa = fmaf(w.x, o0, fmaf(w.y, o1, fmaf(w.z, n0, fmaf(w.w, n1, bb))));
            float pb = fmaf(w.x, n0, fmaf(w.y, n1, fmaf(w.z, o0, fmaf(w.w, o1, bb))));
            ha[i] = fast_tanh(pa);
            hb[i] = fast_tanh(pb);
        }

        LAYER(80,  ha, hb, ta, tb)   // layer 1
        LAYER(352, ta, tb, ha, hb)   // layer 2
        LAYER(624, ha, hb, ta, tb)   // layer 3

        // output layer: 16 -> 1 (reads ta/tb)
        float oa = sw[912], ob = sw[912];
        #pragma unroll
        for (int kk = 0; kk < 4; ++kk) {
            const float4 w = *reinterpret_cast<const float4*>(&sw[896 + kk * 4]);
            oa = fmaf(w.x, ta[4 * kk + 0], oa);
            oa = fmaf(w.y, ta[4 * kk + 1], oa);
            oa = fmaf(w.z, ta[4 * kk + 2], oa);
            oa = fmaf(w.w, ta[4 * kk + 3], oa);
            ob = fmaf(w.x, tb[4 * kk + 0], ob);
            ob = fmaf(w.y, tb[4 * kk + 1], ob);
            ob = fmaf(w.z, tb[4 * kk + 2], ob);
            ob = fmaf(w.w, tb[4 * kk + 3], ob);
        }
        const float tr  = fast_tanh(oa - ob);
        const float fac = (tr < 0.0f) ? o0 : n0;
        sum = fmaf(tr * fac, c_dinv[k], sum);
    }
#undef LAYER

    // pair-reduce the two halves of this voxel (lanes gid and gid^1)
    sum += __shfl_xor(sum, 1);

    if (half == 0) {
        float2 r;
        r.x = fmaf(sum, SCALE, o0);
        r.y = o1;
        reinterpret_cast<float2*>(out)[vox] = r;
    }
}

extern "C" void kernel_launch(void* const* d_in, const int* in_sizes, int n_in,
                              void* d_out, int out_size, void* d_ws, size_t ws_size,
                              hipStream_t stream) {
    const float* q    = (const float*)d_in[0];
    const float* W0   = (const float*)d_in[1];
    const float* b0   = (const float*)d_in[2];
    const float* W1   = (const float*)d_in[3];
    const float* b1   = (const float*)d_in[4];
    const float* W2   = (const float*)d_in[5];
    const float* b2   = (const float*)d_in[6];
    const float* W3   = (const float*)d_in[7];
    const float* b3   = (const float*)d_in[8];
    const float* Wout = (const float*)d_in[9];
    const float* bout = (const float*)d_in[10];
    float* out = (float*)d_out;

    const int threads = 256;
    const int blocks  = (NVOX * 2) / threads;  // 1728 blocks of 256
    automaton_kernel<<<dim3(blocks), dim3(threads), 0, stream>>>(
        q, W0, b0, W1, b1, W2, b2, W3, b3, Wout, bout, out);
}

// Round 3
// 222.304 us; speedup vs baseline: 14.8782x; 14.8782x over previous
//
#include <hip/hip_runtime.h>

static constexpr int NSIDE = 48;
static constexpr int NVOX  = NSIDE * NSIDE * NSIDE;   // 110592
static constexpr float SCALE = 0.041875863808787856f; // ONE_OVER_DIFF_TOT * DIFF_Q

// Neighbor offsets = -SHIFTS (jnp.roll(q, s) => nb[p] = q[p - s]).
// Order matches D_INV: 6 faces (1), 12 edges (1/sqrt2), 8 corners (1/sqrt3).
__device__ __constant__ int c_ox[26] = { 1,-1, 0, 0, 0, 0,
                                         1,-1, 1,-1, 1,-1, 1,-1, 0, 0, 0, 0,
                                         1, 1, 1, 1,-1,-1,-1,-1 };
__device__ __constant__ int c_oy[26] = { 0, 0, 1,-1, 0, 0,
                                         1, 1,-1,-1, 0, 0, 0, 0, 1,-1, 1,-1,
                                         1, 1,-1,-1, 1, 1,-1,-1 };
__device__ __constant__ int c_oz[26] = { 0, 0, 0, 0, 1,-1,
                                         0, 0, 0, 0, 1, 1,-1,-1, 1, 1,-1,-1,
                                         1,-1, 1,-1, 1,-1, 1,-1 };
__device__ __constant__ float c_dinv[26] = {
    1.f, 1.f, 1.f, 1.f, 1.f, 1.f,
    0.70710678118654752f, 0.70710678118654752f, 0.70710678118654752f, 0.70710678118654752f,
    0.70710678118654752f, 0.70710678118654752f, 0.70710678118654752f, 0.70710678118654752f,
    0.70710678118654752f, 0.70710678118654752f, 0.70710678118654752f, 0.70710678118654752f,
    0.57735026918962576f, 0.57735026918962576f, 0.57735026918962576f, 0.57735026918962576f,
    0.57735026918962576f, 0.57735026918962576f, 0.57735026918962576f, 0.57735026918962576f };

__device__ __forceinline__ float fast_tanh(float x) {
    // tanh(x) = 1 - 2/(exp2(2*log2e*x)+1); exact saturation at +-inf.
    float e = __builtin_amdgcn_exp2f(x * 2.8853900817779268f);
    float r = __builtin_amdgcn_rcpf(e + 1.0f);
    return fmaf(-2.0f, r, 1.0f);
}

// LDS weight layout (floats):
//  W0:[0,64) b0:[64,80) W1:[80,336) b1:[336,352) W2:[352,608) b2:[608,624)
//  W3:[624,880) b3:[880,896) Wout:[896,912) bout:[912]
__global__ __launch_bounds__(256)
void automaton_kernel(const float* __restrict__ q,
                      const float* __restrict__ W0, const float* __restrict__ b0,
                      const float* __restrict__ W1, const float* __restrict__ b1,
                      const float* __restrict__ W2, const float* __restrict__ b2,
                      const float* __restrict__ W3, const float* __restrict__ b3,
                      const float* __restrict__ Wout, const float* __restrict__ bout,
                      float* __restrict__ out)
{
    __shared__ __align__(16) float sw[916];
    const int t = threadIdx.x;
    if (t <  64) sw[      t] = W0[t];
    if (t <  16) sw[ 64 + t] = b0[t];
                 sw[ 80 + t] = W1[t];
    if (t <  16) sw[336 + t] = b1[t];
                 sw[352 + t] = W2[t];
    if (t <  16) sw[608 + t] = b2[t];
                 sw[624 + t] = W3[t];
    if (t <  16) sw[880 + t] = b3[t];
    if (t <  16) sw[896 + t] = Wout[t];
    if (t ==  0) sw[912]     = bout[0];
    __syncthreads();

    const int gid  = blockIdx.x * 256 + t;          // 0 .. 221183
    const int vox  = gid >> 1;
    const int half = gid & 1;

    const int z = vox % NSIDE;
    const int y = (vox / NSIDE) % NSIDE;
    const int x = vox / (NSIDE * NSIDE);
    const int xm = (x == 0) ? NSIDE - 1 : x - 1;
    const int xp = (x == NSIDE - 1) ? 0 : x + 1;
    const int ym = (y == 0) ? NSIDE - 1 : y - 1;
    const int yp = (y == NSIDE - 1) ? 0 : y + 1;
    const int zm = (z == 0) ? NSIDE - 1 : z - 1;
    const int zp = (z == NSIDE - 1) ? 0 : z + 1;

    const float2 own = reinterpret_cast<const float2*>(q)[vox];
    const float o0 = own.x, o1 = own.y;

    float ha[16], hb[16], ta[16], tb[16];

// one 16->16 tanh layer on both evals, weights shared per load
#define LAYER(WB, INA, INB, OUTA, OUTB)                                        \
    {                                                                          \
        _Pragma("unroll")                                                      \
        for (int i = 0; i < 16; ++i) {                                         \
            float aa = sw[(WB) + 256 + i];                                     \
            float ab = aa;                                                     \
            _Pragma("unroll")                                                  \
            for (int kk = 0; kk < 4; ++kk) {                                   \
                const float4 w = *reinterpret_cast<const float4*>(             \
                    &sw[(WB) + i * 16 + kk * 4]);                              \
                aa = fmaf(w.x, INA[4 * kk + 0], aa);                           \
                aa = fmaf(w.y, INA[4 * kk + 1], aa);                           \
                aa = fmaf(w.z, INA[4 * kk + 2], aa);                           \
                aa = fmaf(w.w, INA[4 * kk + 3], aa);                           \
                ab = fmaf(w.x, INB[4 * kk + 0], ab);                           \
                ab = fmaf(w.y, INB[4 * kk + 1], ab);                           \
                ab = fmaf(w.z, INB[4 * kk + 2], ab);                           \
                ab = fmaf(w.w, INB[4 * kk + 3], ab);                           \
            }                                                                  \
            OUTA[i] = fast_tanh(aa);                                           \
            OUTB[i] = fast_tanh(ab);                                           \
        }                                                                      \
    }

    float sum = 0.0f;
    #pragma unroll 1
    for (int k = half * 13; k < half * 13 + 13; ++k) {
        // Forbid hoisting loop-invariant LDS weight loads out of the loop:
        // LICM hoisting 916 floats was the source of 3.5-6.5 GB of scratch
        // spill traffic in rounds 1-2. Weights are re-read from LDS each
        // iteration (broadcast, conflict-free); hidden state stays in VGPRs.
        asm volatile("" ::: "memory");

        const int ox = c_ox[k], oy = c_oy[k], oz = c_oz[k];
        const int nx = (ox < 0) ? xm : ((ox > 0) ? xp : x);
        const int ny = (oy < 0) ? ym : ((oy > 0) ? yp : y);
        const int nz = (oz < 0) ? zm : ((oz > 0) ? zp : z);
        const float2 nbq = reinterpret_cast<const float2*>(q)[(nx * NSIDE + ny) * NSIDE + nz];
        const float n0 = nbq.x, n1 = nbq.y;

        // layer 0: 4 -> 16, both orderings share the weight load
        #pragma unroll
        for (int i = 0; i < 16; ++i) {
            const float4 w = *reinterpret_cast<const float4*>(&sw[i * 4]);
            const float bb = sw[64 + i];
            float pa = fmaf(w.x, o0, fmaf(w.y, o1, fmaf(w.z, n0, fmaf(w.w, n1, bb))));
            float pb = fmaf(w.x, n0, fmaf(w.y, n1, fmaf(w.z, o0, fmaf(w.w, o1, bb))));
            ha[i] = fast_tanh(pa);
            hb[i] = fast_tanh(pb);
        }

        LAYER(80,  ha, hb, ta, tb)   // layer 1
        LAYER(352, ta, tb, ha, hb)   // layer 2
        LAYER(624, ha, hb, ta, tb)   // layer 3

        // output layer: 16 -> 1 (reads ta/tb)
        float oa = sw[912], ob = sw[912];
        #pragma unroll
        for (int kk = 0; kk < 4; ++kk) {
            const float4 w = *reinterpret_cast<const float4*>(&sw[896 + kk * 4]);
            oa = fmaf(w.x, ta[4 * kk + 0], oa);
            oa = fmaf(w.y, ta[4 * kk + 1], oa);
            oa = fmaf(w.z, ta[4 * kk + 2], oa);
            oa = fmaf(w.w, ta[4 * kk + 3], oa);
            ob = fmaf(w.x, tb[4 * kk + 0], ob);
            ob = fmaf(w.y, tb[4 * kk + 1], ob);
            ob = fmaf(w.z, tb[4 * kk + 2], ob);
            ob = fmaf(w.w, tb[4 * kk + 3], ob);
        }
        const float tr  = fast_tanh(oa - ob);
        const float fac = (tr < 0.0f) ? o0 : n0;
        sum = fmaf(tr * fac, c_dinv[k], sum);
    }
#undef LAYER

    // pair-reduce the two halves of this voxel (lanes gid and gid^1)
    sum += __shfl_xor(sum, 1);

    if (half == 0) {
        float2 r;
        r.x = fmaf(sum, SCALE, o0);
        r.y = o1;
        reinterpret_cast<float2*>(out)[vox] = r;
    }
}

extern "C" void kernel_launch(void* const* d_in, const int* in_sizes, int n_in,
                              void* d_out, int out_size, void* d_ws, size_t ws_size,
                              hipStream_t stream) {
    const float* q    = (const float*)d_in[0];
    const float* W0   = (const float*)d_in[1];
    const float* b0   = (const float*)d_in[2];
    const float* W1   = (const float*)d_in[3];
    const float* b1   = (const float*)d_in[4];
    const float* W2   = (const float*)d_in[5];
    const float* b2   = (const float*)d_in[6];
    const float* W3   = (const float*)d_in[7];
    const float* b3   = (const float*)d_in[8];
    const float* Wout = (const float*)d_in[9];
    const float* bout = (const float*)d_in[10];
    float* out = (float*)d_out;

    const int threads = 256;
    const int blocks  = (NVOX * 2) / threads;  // 1728 blocks of 256
    automaton_kernel<<<dim3(blocks), dim3(threads), 0, stream>>>(
        q, W0, b0, W1, b1, W2, b2, W3, b3, Wout, bout, out);
}

// Round 4
// 85.966 us; speedup vs baseline: 38.4743x; 2.5859x over previous
//
#include <hip/hip_runtime.h>

static constexpr int NSIDE = 48;
static constexpr int NVOX  = NSIDE * NSIDE * NSIDE;   // 110592
static constexpr float SCALE = 0.041875863808787856f; // ONE_OVER_DIFF_TOT * DIFF_Q
static constexpr int NDIR  = 13;                      // canonical half of the 26 offsets
static constexpr int BLOCKS_PER_DIR = NVOX / 256;     // 432

// Canonical directions (first nonzero component positive).
// 3 faces (dinv 1), 6 edges (1/sqrt2), 4 corners (1/sqrt3).
__device__ __constant__ int g_ox[NDIR] = { 1, 0, 0,  1, 1, 1, 1, 0, 0,  1, 1, 1, 1 };
__device__ __constant__ int g_oy[NDIR] = { 0, 1, 0,  1,-1, 0, 0, 1, 1,  1, 1,-1,-1 };
__device__ __constant__ int g_oz[NDIR] = { 0, 0, 1,  0, 0, 1,-1, 1,-1,  1,-1, 1,-1 };
__device__ __constant__ float g_dinv[NDIR] = {
    1.f, 1.f, 1.f,
    0.70710678118654752f, 0.70710678118654752f, 0.70710678118654752f,
    0.70710678118654752f, 0.70710678118654752f, 0.70710678118654752f,
    0.57735026918962576f, 0.57735026918962576f, 0.57735026918962576f, 0.57735026918962576f };

// Full 26-neighbor tables for the fallback single-pass kernel.
__device__ __constant__ int c_ox[26] = { 1,-1, 0, 0, 0, 0,
                                         1,-1, 1,-1, 1,-1, 1,-1, 0, 0, 0, 0,
                                         1, 1, 1, 1,-1,-1,-1,-1 };
__device__ __constant__ int c_oy[26] = { 0, 0, 1,-1, 0, 0,
                                         1, 1,-1,-1, 0, 0, 0, 0, 1,-1, 1,-1,
                                         1, 1,-1,-1, 1, 1,-1,-1 };
__device__ __constant__ int c_oz[26] = { 0, 0, 0, 0, 1,-1,
                                         0, 0, 0, 0, 1, 1,-1,-1, 1, 1,-1,-1,
                                         1,-1, 1,-1, 1,-1, 1,-1 };
__device__ __constant__ float c_dinv[26] = {
    1.f, 1.f, 1.f, 1.f, 1.f, 1.f,
    0.70710678118654752f, 0.70710678118654752f, 0.70710678118654752f, 0.70710678118654752f,
    0.70710678118654752f, 0.70710678118654752f, 0.70710678118654752f, 0.70710678118654752f,
    0.70710678118654752f, 0.70710678118654752f, 0.70710678118654752f, 0.70710678118654752f,
    0.57735026918962576f, 0.57735026918962576f, 0.57735026918962576f, 0.57735026918962576f,
    0.57735026918962576f, 0.57735026918962576f, 0.57735026918962576f, 0.57735026918962576f };

__device__ __forceinline__ float fast_tanh(float x) {
    // tanh(x) = 1 - 2/(exp2(2*log2e*x)+1); exact saturation at +-inf.
    float e = __builtin_amdgcn_exp2f(x * 2.8853900817779268f);
    float r = __builtin_amdgcn_rcpf(e + 1.0f);
    return fmaf(-2.0f, r, 1.0f);
}

// LDS weight layout (floats):
//  W0:[0,64) b0:[64,80) W1:[80,336) b1:[336,352) W2:[352,608) b2:[608,624)
//  W3:[624,880) b3:[880,896) Wout:[896,912) bout:[912]
#define STAGE_WEIGHTS()                                                        \
    __shared__ __align__(16) float sw[916];                                    \
    {                                                                          \
        const int t_ = threadIdx.x;                                            \
        if (t_ <  64) sw[      t_] = W0[t_];                                   \
        if (t_ <  16) sw[ 64 + t_] = b0[t_];                                   \
                      sw[ 80 + t_] = W1[t_];                                   \
        if (t_ <  16) sw[336 + t_] = b1[t_];                                   \
                      sw[352 + t_] = W2[t_];                                   \
        if (t_ <  16) sw[608 + t_] = b2[t_];                                   \
                      sw[624 + t_] = W3[t_];                                   \
        if (t_ <  16) sw[880 + t_] = b3[t_];                                   \
        if (t_ <  16) sw[896 + t_] = Wout[t_];                                 \
        if (t_ ==  0) sw[912]     = bout[0];                                   \
        __syncthreads();                                                       \
    }

// one 16->16 tanh layer on both evals, weights shared per load
#define LAYER(WB, INA, INB, OUTA, OUTB)                                        \
    {                                                                          \
        _Pragma("unroll")                                                      \
        for (int i = 0; i < 16; ++i) {                                         \
            float aa = sw[(WB) + 256 + i];                                     \
            float ab = aa;                                                     \
            _Pragma("unroll")                                                  \
            for (int kk = 0; kk < 4; ++kk) {                                   \
                const float4 w = *reinterpret_cast<const float4*>(             \
                    &sw[(WB) + i * 16 + kk * 4]);                              \
                aa = fmaf(w.x, INA[4 * kk + 0], aa);                           \
                aa = fmaf(w.y, INA[4 * kk + 1], aa);                           \
                aa = fmaf(w.z, INA[4 * kk + 2], aa);                           \
                aa = fmaf(w.w, INA[4 * kk + 3], aa);                           \
                ab = fmaf(w.x, INB[4 * kk + 0], ab);                           \
                ab = fmaf(w.y, INB[4 * kk + 1], ab);                           \
                ab = fmaf(w.z, INB[4 * kk + 2], ab);                           \
                ab = fmaf(w.w, INB[4 * kk + 3], ab);                           \
            }                                                                  \
            OUTA[i] = fast_tanh(aa);                                           \
            OUTB[i] = fast_tanh(ab);                                           \
        }                                                                      \
    }

// Both MLP evals for one (own, nb) pair -> signed transfer value.
// Returns t = tanh(M(own,nb) - M(nb,own)).
#define PAIR_EVAL(O0, O1, N0, N1, TROUT)                                       \
    {                                                                          \
        float ha[16], hb[16], ta[16], tb[16];                                  \
        _Pragma("unroll")                                                      \
        for (int i = 0; i < 16; ++i) {                                         \
            const float4 w = *reinterpret_cast<const float4*>(&sw[i * 4]);     \
            const float bb = sw[64 + i];                                       \
            float pa = fmaf(w.x, O0, fmaf(w.y, O1, fmaf(w.z, N0, fmaf(w.w, N1, bb)))); \
            float pb = fmaf(w.x, N0, fmaf(w.y, N1, fmaf(w.z, O0, fmaf(w.w, O1, bb)))); \
            ha[i] = fast_tanh(pa);                                             \
            hb[i] = fast_tanh(pb);                                             \
        }                                                                      \
        LAYER(80,  ha, hb, ta, tb)                                             \
        LAYER(352, ta, tb, ha, hb)                                             \
        LAYER(624, ha, hb, ta, tb)                                             \
        float oa = sw[912], ob = sw[912];                                      \
        _Pragma("unroll")                                                      \
        for (int kk = 0; kk < 4; ++kk) {                                       \
            const float4 w = *reinterpret_cast<const float4*>(&sw[896 + kk * 4]); \
            oa = fmaf(w.x, ta[4 * kk + 0], oa);                                \
            oa = fmaf(w.y, ta[4 * kk + 1], oa);                                \
            oa = fmaf(w.z, ta[4 * kk + 2], oa);                                \
            oa = fmaf(w.w, ta[4 * kk + 3], oa);                                \
            ob = fmaf(w.x, tb[4 * kk + 0], ob);                                \
            ob = fmaf(w.y, tb[4 * kk + 1], ob);                                \
            ob = fmaf(w.z, tb[4 * kk + 2], ob);                                \
            ob = fmaf(w.w, tb[4 * kk + 3], ob);                                \
        }                                                                      \
        TROUT = fast_tanh(oa - ob);                                            \
    }

// ---------------------------------------------------------------------------
// Pass 1: one thread per (direction k, voxel v). Computes the directed flux
// f = t * factor * dinv for the pair (v, v + d_k) and stores it to
// ws[k*NVOX + v]. Flux is exactly antisymmetric, so each pair is evaluated
// once (13 directions instead of 26 neighbors -> 2x less MLP work).
__global__ __launch_bounds__(256)
void flux_kernel(const float* __restrict__ q,
                 const float* __restrict__ W0, const float* __restrict__ b0,
                 const float* __restrict__ W1, const float* __restrict__ b1,
                 const float* __restrict__ W2, const float* __restrict__ b2,
                 const float* __restrict__ W3, const float* __restrict__ b3,
                 const float* __restrict__ Wout, const float* __restrict__ bout,
                 float* __restrict__ ws)
{
    STAGE_WEIGHTS()

    const int k   = blockIdx.x / BLOCKS_PER_DIR;                 // 0..12
    const int vox = (blockIdx.x - k * BLOCKS_PER_DIR) * 256 + threadIdx.x;

    const int z = vox % NSIDE;
    const int y = (vox / NSIDE) % NSIDE;
    const int x = vox / (NSIDE * NSIDE);

    const int ox = g_ox[k], oy = g_oy[k], oz = g_oz[k];
    const int nx = (ox > 0) ? ((x == NSIDE - 1) ? 0 : x + 1) : x;   // ox in {0,1}
    const int ny = (oy > 0) ? ((y == NSIDE - 1) ? 0 : y + 1)
                            : ((oy < 0) ? ((y == 0) ? NSIDE - 1 : y - 1) : y);
    const int nz = (oz > 0) ? ((z == NSIDE - 1) ? 0 : z + 1)
                            : ((oz < 0) ? ((z == 0) ? NSIDE - 1 : z - 1) : z);

    const float2 own = reinterpret_cast<const float2*>(q)[vox];
    const float2 nbq = reinterpret_cast<const float2*>(q)[(nx * NSIDE + ny) * NSIDE + nz];
    const float o0 = own.x, o1 = own.y;
    const float n0 = nbq.x, n1 = nbq.y;

    float tr;
    PAIR_EVAL(o0, o1, n0, n1, tr)

    const float fac = (tr < 0.0f) ? o0 : n0;
    ws[k * NVOX + vox] = tr * fac * g_dinv[k];
}

// ---------------------------------------------------------------------------
// Pass 2: per voxel u, total = sum_k ( f[k][u] - f[k][u - d_k] ).
__global__ __launch_bounds__(256)
void gather_kernel(const float* __restrict__ q,
                   const float* __restrict__ ws,
                   float* __restrict__ out)
{
    const int vox = blockIdx.x * 256 + threadIdx.x;

    const int z = vox % NSIDE;
    const int y = (vox / NSIDE) % NSIDE;
    const int x = vox / (NSIDE * NSIDE);
    const int xm = (x == 0) ? NSIDE - 1 : x - 1;
    const int ym = (y == 0) ? NSIDE - 1 : y - 1;
    const int yp = (y == NSIDE - 1) ? 0 : y + 1;
    const int zm = (z == 0) ? NSIDE - 1 : z - 1;
    const int zp = (z == NSIDE - 1) ? 0 : z + 1;

    float s = 0.0f;
    #pragma unroll
    for (int k = 0; k < NDIR; ++k) {
        const int px = g_ox[k] ? xm : x;                       // ox in {0,1}
        const int py = (g_oy[k] > 0) ? ym : ((g_oy[k] < 0) ? yp : y);
        const int pz = (g_oz[k] > 0) ? zm : ((g_oz[k] < 0) ? zp : z);
        s += ws[k * NVOX + vox];
        s -= ws[k * NVOX + (px * NSIDE + py) * NSIDE + pz];
    }

    const float2 own = reinterpret_cast<const float2*>(q)[vox];
    float2 r;
    r.x = fmaf(s, SCALE, own.x);
    r.y = own.y;
    reinterpret_cast<float2*>(out)[vox] = r;
}

// ---------------------------------------------------------------------------
// Fallback: Round-3 single-pass kernel (used only if ws is too small).
__global__ __launch_bounds__(256)
void automaton_kernel(const float* __restrict__ q,
                      const float* __restrict__ W0, const float* __restrict__ b0,
                      const float* __restrict__ W1, const float* __restrict__ b1,
                      const float* __restrict__ W2, const float* __restrict__ b2,
                      const float* __restrict__ W3, const float* __restrict__ b3,
                      const float* __restrict__ Wout, const float* __restrict__ bout,
                      float* __restrict__ out)
{
    STAGE_WEIGHTS()

    const int gid  = blockIdx.x * 256 + threadIdx.x;
    const int vox  = gid >> 1;
    const int half = gid & 1;

    const int z = vox % NSIDE;
    const int y = (vox / NSIDE) % NSIDE;
    const int x = vox / (NSIDE * NSIDE);
    const int xm = (x == 0) ? NSIDE - 1 : x - 1;
    const int xp = (x == NSIDE - 1) ? 0 : x + 1;
    const int ym = (y == 0) ? NSIDE - 1 : y - 1;
    const int yp = (y == NSIDE - 1) ? 0 : y + 1;
    const int zm = (z == 0) ? NSIDE - 1 : z - 1;
    const int zp = (z == NSIDE - 1) ? 0 : z + 1;

    const float2 own = reinterpret_cast<const float2*>(q)[vox];
    const float o0 = own.x, o1 = own.y;

    float sum = 0.0f;
    #pragma unroll 1
    for (int k = half * 13; k < half * 13 + 13; ++k) {
        asm volatile("" ::: "memory");   // block cross-iteration LICM of weight loads
        const int ox = c_ox[k], oy = c_oy[k], oz = c_oz[k];
        const int nx = (ox < 0) ? xm : ((ox > 0) ? xp : x);
        const int ny = (oy < 0) ? ym : ((oy > 0) ? yp : y);
        const int nz = (oz < 0) ? zm : ((oz > 0) ? zp : z);
        const float2 nbq = reinterpret_cast<const float2*>(q)[(nx * NSIDE + ny) * NSIDE + nz];
        const float n0 = nbq.x, n1 = nbq.y;

        float tr;
        PAIR_EVAL(o0, o1, n0, n1, tr)
        const float fac = (tr < 0.0f) ? o0 : n0;
        sum = fmaf(tr * fac, c_dinv[k], sum);
    }

    sum += __shfl_xor(sum, 1);
    if (half == 0) {
        float2 r;
        r.x = fmaf(sum, SCALE, o0);
        r.y = o1;
        reinterpret_cast<float2*>(out)[vox] = r;
    }
}

extern "C" void kernel_launch(void* const* d_in, const int* in_sizes, int n_in,
                              void* d_out, int out_size, void* d_ws, size_t ws_size,
                              hipStream_t stream) {
    const float* q    = (const float*)d_in[0];
    const float* W0   = (const float*)d_in[1];
    const float* b0   = (const float*)d_in[2];
    const float* W1   = (const float*)d_in[3];
    const float* b1   = (const float*)d_in[4];
    const float* W2   = (const float*)d_in[5];
    const float* b2   = (const float*)d_in[6];
    const float* W3   = (const float*)d_in[7];
    const float* b3   = (const float*)d_in[8];
    const float* Wout = (const float*)d_in[9];
    const float* bout = (const float*)d_in[10];
    float* out = (float*)d_out;

    const size_t ws_needed = (size_t)NDIR * NVOX * sizeof(float);  // 5.75 MB
    if (ws_size >= ws_needed) {
        float* ws = (float*)d_ws;
        flux_kernel<<<dim3(NDIR * BLOCKS_PER_DIR), dim3(256), 0, stream>>>(
            q, W0, b0, W1, b1, W2, b2, W3, b3, Wout, bout, ws);
        gather_kernel<<<dim3(NVOX / 256), dim3(256), 0, stream>>>(q, ws, out);
    } else {
        automaton_kernel<<<dim3(NVOX * 2 / 256), dim3(256), 0, stream>>>(
            q, W0, b0, W1, b1, W2, b2, W3, b3, Wout, bout, out);
    }
}

// Round 5
// 63.804 us; speedup vs baseline: 51.8379x; 1.3473x over previous
//
#include <hip/hip_runtime.h>

static constexpr int NSIDE = 48;
static constexpr int NVOX  = NSIDE * NSIDE * NSIDE;   // 110592
static constexpr float SCALE = 0.041875863808787856f; // ONE_OVER_DIFF_TOT * DIFF_Q
static constexpr int NDIR  = 13;                      // canonical half of the 26 offsets
static constexpr int PAIRS_PER_BLOCK = 128;           // 4 waves x 32 pairs
static constexpr int BLOCKS_PER_DIR  = NVOX / PAIRS_PER_BLOCK;  // 864

typedef _Float16 f16x8 __attribute__((ext_vector_type(8)));
typedef float    f32x16 __attribute__((ext_vector_type(16)));

// Canonical directions (first nonzero component positive).
__device__ __constant__ int g_ox[NDIR] = { 1, 0, 0,  1, 1, 1, 1, 0, 0,  1, 1, 1, 1 };
__device__ __constant__ int g_oy[NDIR] = { 0, 1, 0,  1,-1, 0, 0, 1, 1,  1, 1,-1,-1 };
__device__ __constant__ int g_oz[NDIR] = { 0, 0, 1,  0, 0, 1,-1, 1,-1,  1,-1, 1,-1 };
__device__ __constant__ float g_dinv[NDIR] = {
    1.f, 1.f, 1.f,
    0.70710678118654752f, 0.70710678118654752f, 0.70710678118654752f,
    0.70710678118654752f, 0.70710678118654752f, 0.70710678118654752f,
    0.57735026918962576f, 0.57735026918962576f, 0.57735026918962576f, 0.57735026918962576f };

// Full 26-neighbor tables for the fallback single-pass kernel.
__device__ __constant__ int c_ox[26] = { 1,-1, 0, 0, 0, 0,
                                         1,-1, 1,-1, 1,-1, 1,-1, 0, 0, 0, 0,
                                         1, 1, 1, 1,-1,-1,-1,-1 };
__device__ __constant__ int c_oy[26] = { 0, 0, 1,-1, 0, 0,
                                         1, 1,-1,-1, 0, 0, 0, 0, 1,-1, 1,-1,
                                         1, 1,-1,-1, 1, 1,-1,-1 };
__device__ __constant__ int c_oz[26] = { 0, 0, 0, 0, 1,-1,
                                         0, 0, 0, 0, 1, 1,-1,-1, 1, 1,-1,-1,
                                         1,-1, 1,-1, 1,-1, 1,-1 };
__device__ __constant__ float c_dinv[26] = {
    1.f, 1.f, 1.f, 1.f, 1.f, 1.f,
    0.70710678118654752f, 0.70710678118654752f, 0.70710678118654752f, 0.70710678118654752f,
    0.70710678118654752f, 0.70710678118654752f, 0.70710678118654752f, 0.70710678118654752f,
    0.70710678118654752f, 0.70710678118654752f, 0.70710678118654752f, 0.70710678118654752f,
    0.57735026918962576f, 0.57735026918962576f, 0.57735026918962576f, 0.57735026918962576f,
    0.57735026918962576f, 0.57735026918962576f, 0.57735026918962576f, 0.57735026918962576f };

__device__ __forceinline__ float fast_tanh(float x) {
    float e = __builtin_amdgcn_exp2f(x * 2.8853900817779268f);
    float r = __builtin_amdgcn_rcpf(e + 1.0f);
    return fmaf(-2.0f, r, 1.0f);
}

// LDS weight layout (floats):
//  W0:[0,64) b0:[64,80) W1:[80,336) b1:[336,352) W2:[352,608) b2:[608,624)
//  W3:[624,880) b3:[880,896) Wout:[896,912) bout:[912]
#define STAGE_WEIGHTS()                                                        \
    __shared__ __align__(16) float sw[916];                                    \
    {                                                                          \
        const int t_ = threadIdx.x;                                            \
        if (t_ <  64) sw[      t_] = W0[t_];                                   \
        if (t_ <  16) sw[ 64 + t_] = b0[t_];                                   \
                      sw[ 80 + t_] = W1[t_];                                   \
        if (t_ <  16) sw[336 + t_] = b1[t_];                                   \
                      sw[352 + t_] = W2[t_];                                   \
        if (t_ <  16) sw[608 + t_] = b2[t_];                                   \
                      sw[624 + t_] = W3[t_];                                   \
        if (t_ <  16) sw[880 + t_] = b3[t_];                                   \
        if (t_ <  16) sw[896 + t_] = Wout[t_];                                 \
        if (t_ ==  0) sw[912]     = bout[0];                                   \
        __syncthreads();                                                       \
    }

// sigma(g,p): the k-index owned by lane-group g, fragment slot p. The SAME
// convention is used to build A (weights) and is what D-chaining delivers for
// B, so any mismatch vs the HW's internal k-order cancels in the contraction.
#define SIG(G, P) (((P) < 4) ? 4 * (G) + (P) : 8 + 4 * (G) + ((P) - 4))

// ---------------------------------------------------------------------------
// MFMA flux kernel. Each wave: 32 pairs = 64 MLP instances (eval-a cols in
// one MFMA, eval-b in another). Hidden layers: D[32x32] = Wpad[32x16]*X[16x32]
// via v_mfma_f32_32x32x16_f16, bias in C, f32 accumulation. D reg r of lane l
// holds feature m = (r&3)+8*(r>>2)+4*(l>>5) of instance n = l&31 -- exactly
// the B-fragment k-set for the next layer in the same order: chain with zero
// cross-lane data movement.
__global__ __launch_bounds__(256)
void flux_mfma_kernel(const float* __restrict__ q,
                      const float* __restrict__ W0, const float* __restrict__ b0,
                      const float* __restrict__ W1, const float* __restrict__ b1,
                      const float* __restrict__ W2, const float* __restrict__ b2,
                      const float* __restrict__ W3, const float* __restrict__ b3,
                      const float* __restrict__ Wout, const float* __restrict__ bout,
                      float* __restrict__ ws)
{
    STAGE_WEIGHTS()

    const int k    = blockIdx.x / BLOCKS_PER_DIR;                // 0..12
    const int rem  = blockIdx.x - k * BLOCKS_PER_DIR;
    const int lane = threadIdx.x & 63;
    const int wv   = threadIdx.x >> 6;
    const int g    = lane >> 5;                                  // lane-group 0/1
    const int vox  = rem * PAIRS_PER_BLOCK + wv * 32 + (lane & 31);

    const int z = vox % NSIDE;
    const int y = (vox / NSIDE) % NSIDE;
    const int x = vox / (NSIDE * NSIDE);
    const int ox = g_ox[k], oy = g_oy[k], oz = g_oz[k];
    const int nx = (ox > 0) ? ((x == NSIDE - 1) ? 0 : x + 1) : x;   // ox in {0,1}
    const int ny = (oy > 0) ? ((y == NSIDE - 1) ? 0 : y + 1)
                            : ((oy < 0) ? ((y == 0) ? NSIDE - 1 : y - 1) : y);
    const int nz = (oz > 0) ? ((z == NSIDE - 1) ? 0 : z + 1)
                            : ((oz < 0) ? ((z == 0) ? NSIDE - 1 : z - 1) : z);

    const float2 own = reinterpret_cast<const float2*>(q)[vox];
    const float2 nbq = reinterpret_cast<const float2*>(q)[(nx * NSIDE + ny) * NSIDE + nz];
    const float o0 = own.x, o1 = own.y;
    const float n0 = nbq.x, n1 = nbq.y;

    // --- loop-invariant fragments: hidden-layer weights (A) and biases (C) ---
    const int row = lane & 31;        // A row; rows >=16 are don't-care
    const int wr  = (row & 15) * 16;
    f16x8 aw1, aw2, aw3;
    f32x16 c1, c2, c3;
    #pragma unroll
    for (int p = 0; p < 8; ++p) {
        const int kk = SIG(g, p);
        aw1[p] = (_Float16)sw[ 80 + wr + kk];
        aw2[p] = (_Float16)sw[352 + wr + kk];
        aw3[p] = (_Float16)sw[624 + wr + kk];
        c1[p] = sw[336 + kk];   // b1[sigma(g,p)] = bias of feature this lane owns in D
        c2[p] = sw[608 + kk];
        c3[p] = sw[880 + kk];
    }
    #pragma unroll
    for (int p = 8; p < 16; ++p) { c1[p] = 0.0f; c2[p] = 0.0f; c3[p] = 0.0f; }
    float woutv[8];
    #pragma unroll
    for (int p = 0; p < 8; ++p) woutv[p] = sw[896 + SIG(g, p)];

    // --- layer 0 (4 -> 16) on VALU, directly into B-fragment layout ---
    f16x8 ba, bb;
    #pragma unroll
    for (int p = 0; p < 8; ++p) {
        const int f = SIG(g, p);
        const float4 w = *reinterpret_cast<const float4*>(&sw[f * 4]);
        const float bbias = sw[64 + f];
        float pa = fmaf(w.x, o0, fmaf(w.y, o1, fmaf(w.z, n0, fmaf(w.w, n1, bbias))));
        float pb = fmaf(w.x, n0, fmaf(w.y, n1, fmaf(w.z, o0, fmaf(w.w, o1, bbias))));
        ba[p] = (_Float16)fast_tanh(pa);
        bb[p] = (_Float16)fast_tanh(pb);
    }

    // --- hidden layers 1..3 on MFMA ---
    f32x16 da, db;
    da = __builtin_amdgcn_mfma_f32_32x32x16_f16(aw1, ba, c1, 0, 0, 0);
    db = __builtin_amdgcn_mfma_f32_32x32x16_f16(aw1, bb, c1, 0, 0, 0);
    #pragma unroll
    for (int p = 0; p < 8; ++p) {
        ba[p] = (_Float16)fast_tanh(da[p]);
        bb[p] = (_Float16)fast_tanh(db[p]);
    }
    da = __builtin_amdgcn_mfma_f32_32x32x16_f16(aw2, ba, c2, 0, 0, 0);
    db = __builtin_amdgcn_mfma_f32_32x32x16_f16(aw2, bb, c2, 0, 0, 0);
    #pragma unroll
    for (int p = 0; p < 8; ++p) {
        ba[p] = (_Float16)fast_tanh(da[p]);
        bb[p] = (_Float16)fast_tanh(db[p]);
    }
    da = __builtin_amdgcn_mfma_f32_32x32x16_f16(aw3, ba, c3, 0, 0, 0);
    db = __builtin_amdgcn_mfma_f32_32x32x16_f16(aw3, bb, c3, 0, 0, 0);

    // --- output head (16 -> 1): partial dot over this lane's 8 features,
    //     complement comes from lane^32. bout cancels in (oa - ob).
    float pa = 0.0f, pb = 0.0f;
    #pragma unroll
    for (int p = 0; p < 8; ++p) {
        pa = fmaf(fast_tanh(da[p]), woutv[p], pa);
        pb = fmaf(fast_tanh(db[p]), woutv[p], pb);
    }
    pa += __shfl_xor(pa, 32);
    pb += __shfl_xor(pb, 32);

    const float tr  = fast_tanh(pa - pb);
    const float fac = (tr < 0.0f) ? o0 : n0;
    if ((lane & 63) < 32)
        ws[k * NVOX + vox] = tr * fac * g_dinv[k];
}

// ---------------------------------------------------------------------------
// Pass 2: per voxel u, total = sum_k ( f[k][u] - f[k][u - d_k] ).
__global__ __launch_bounds__(256)
void gather_kernel(const float* __restrict__ q,
                   const float* __restrict__ ws,
                   float* __restrict__ out)
{
    const int vox = blockIdx.x * 256 + threadIdx.x;

    const int z = vox % NSIDE;
    const int y = (vox / NSIDE) % NSIDE;
    const int x = vox / (NSIDE * NSIDE);
    const int xm = (x == 0) ? NSIDE - 1 : x - 1;
    const int ym = (y == 0) ? NSIDE - 1 : y - 1;
    const int yp = (y == NSIDE - 1) ? 0 : y + 1;
    const int zm = (z == 0) ? NSIDE - 1 : z - 1;
    const int zp = (z == NSIDE - 1) ? 0 : z + 1;

    float s = 0.0f;
    #pragma unroll
    for (int k = 0; k < NDIR; ++k) {
        const int px = g_ox[k] ? xm : x;
        const int py = (g_oy[k] > 0) ? ym : ((g_oy[k] < 0) ? yp : y);
        const int pz = (g_oz[k] > 0) ? zm : ((g_oz[k] < 0) ? zp : z);
        s += ws[k * NVOX + vox];
        s -= ws[k * NVOX + (px * NSIDE + py) * NSIDE + pz];
    }

    const float2 own = reinterpret_cast<const float2*>(q)[vox];
    float2 r;
    r.x = fmaf(s, SCALE, own.x);
    r.y = own.y;
    reinterpret_cast<float2*>(out)[vox] = r;
}

// ---------------------------------------------------------------------------
// Fallback: Round-3 single-pass scalar kernel (used only if ws is too small).
#define LAYER(WB, INA, INB, OUTA, OUTB)                                        \
    {                                                                          \
        _Pragma("unroll")                                                      \
        for (int i = 0; i < 16; ++i) {                                         \
            float aa = sw[(WB) + 256 + i];                                     \
            float ab = aa;                                                     \
            _Pragma("unroll")                                                  \
            for (int kk = 0; kk < 4; ++kk) {                                   \
                const float4 w = *reinterpret_cast<const float4*>(             \
                    &sw[(WB) + i * 16 + kk * 4]);                              \
                aa = fmaf(w.x, INA[4 * kk + 0], aa);                           \
                aa = fmaf(w.y, INA[4 * kk + 1], aa);                           \
                aa = fmaf(w.z, INA[4 * kk + 2], aa);                           \
                aa = fmaf(w.w, INA[4 * kk + 3], aa);                           \
                ab = fmaf(w.x, INB[4 * kk + 0], ab);                           \
                ab = fmaf(w.y, INB[4 * kk + 1], ab);                           \
                ab = fmaf(w.z, INB[4 * kk + 2], ab);                           \
                ab = fmaf(w.w, INB[4 * kk + 3], ab);                           \
            }                                                                  \
            OUTA[i] = fast_tanh(aa);                                           \
            OUTB[i] = fast_tanh(ab);                                           \
        }                                                                      \
    }

__global__ __launch_bounds__(256)
void automaton_kernel(const float* __restrict__ q,
                      const float* __restrict__ W0, const float* __restrict__ b0,
                      const float* __restrict__ W1, const float* __restrict__ b1,
                      const float* __restrict__ W2, const float* __restrict__ b2,
                      const float* __restrict__ W3, const float* __restrict__ b3,
                      const float* __restrict__ Wout, const float* __restrict__ bout,
                      float* __restrict__ out)
{
    STAGE_WEIGHTS()

    const int gid  = blockIdx.x * 256 + threadIdx.x;
    const int vox  = gid >> 1;
    const int half = gid & 1;

    const int z = vox % NSIDE;
    const int y = (vox / NSIDE) % NSIDE;
    const int x = vox / (NSIDE * NSIDE);
    const int xm = (x == 0) ? NSIDE - 1 : x - 1;
    const int xp = (x == NSIDE - 1) ? 0 : x + 1;
    const int ym = (y == 0) ? NSIDE - 1 : y - 1;
    const int yp = (y == NSIDE - 1) ? 0 : y + 1;
    const int zm = (z == 0) ? NSIDE - 1 : z - 1;
    const int zp = (z == NSIDE - 1) ? 0 : z + 1;

    const float2 own = reinterpret_cast<const float2*>(q)[vox];
    const float o0 = own.x, o1 = own.y;

    float sum = 0.0f;
    #pragma unroll 1
    for (int k = half * 13; k < half * 13 + 13; ++k) {
        asm volatile("" ::: "memory");   // block cross-iteration LICM of weight loads
        const int ox = c_ox[k], oy = c_oy[k], oz = c_oz[k];
        const int nx = (ox < 0) ? xm : ((ox > 0) ? xp : x);
        const int ny = (oy < 0) ? ym : ((oy > 0) ? yp : y);
        const int nz = (oz < 0) ? zm : ((oz > 0) ? zp : z);
        const float2 nbq = reinterpret_cast<const float2*>(q)[(nx * NSIDE + ny) * NSIDE + nz];
        const float n0 = nbq.x, n1 = nbq.y;

        float ha[16], hb[16], ta[16], tb[16];
        #pragma unroll
        for (int i = 0; i < 16; ++i) {
            const float4 w = *reinterpret_cast<const float4*>(&sw[i * 4]);
            const float bbias = sw[64 + i];
            float pa = fmaf(w.x, o0, fmaf(w.y, o1, fmaf(w.z, n0, fmaf(w.w, n1, bbias))));
            float pb = fmaf(w.x, n0, fmaf(w.y, n1, fmaf(w.z, o0, fmaf(w.w, o1, bbias))));
            ha[i] = fast_tanh(pa);
            hb[i] = fast_tanh(pb);
        }
        LAYER(80,  ha, hb, ta, tb)
        LAYER(352, ta, tb, ha, hb)
        LAYER(624, ha, hb, ta, tb)
        float oa = sw[912], ob = sw[912];
        #pragma unroll
        for (int kk = 0; kk < 4; ++kk) {
            const float4 w = *reinterpret_cast<const float4*>(&sw[896 + kk * 4]);
            oa = fmaf(w.x, ta[4 * kk + 0], oa);
            oa = fmaf(w.y, ta[4 * kk + 1], oa);
            oa = fmaf(w.z, ta[4 * kk + 2], oa);
            oa = fmaf(w.w, ta[4 * kk + 3], oa);
            ob = fmaf(w.x, tb[4 * kk + 0], ob);
            ob = fmaf(w.y, tb[4 * kk + 1], ob);
            ob = fmaf(w.z, tb[4 * kk + 2], ob);
            ob = fmaf(w.w, tb[4 * kk + 3], ob);
        }
        const float tr  = fast_tanh(oa - ob);
        const float fac = (tr < 0.0f) ? o0 : n0;
        sum = fmaf(tr * fac, c_dinv[k], sum);
    }

    sum += __shfl_xor(sum, 1);
    if (half == 0) {
        float2 r;
        r.x = fmaf(sum, SCALE, o0);
        r.y = o1;
        reinterpret_cast<float2*>(out)[vox] = r;
    }
}

extern "C" void kernel_launch(void* const* d_in, const int* in_sizes, int n_in,
                              void* d_out, int out_size, void* d_ws, size_t ws_size,
                              hipStream_t stream) {
    const float* q    = (const float*)d_in[0];
    const float* W0   = (const float*)d_in[1];
    const float* b0   = (const float*)d_in[2];
    const float* W1   = (const float*)d_in[3];
    const float* b1   = (const float*)d_in[4];
    const float* W2   = (const float*)d_in[5];
    const float* b2   = (const float*)d_in[6];
    const float* W3   = (const float*)d_in[7];
    const float* b3   = (const float*)d_in[8];
    const float* Wout = (const float*)d_in[9];
    const float* bout = (const float*)d_in[10];
    float* out = (float*)d_out;

    const size_t ws_needed = (size_t)NDIR * NVOX * sizeof(float);  // 5.75 MB
    if (ws_size >= ws_needed) {
        float* ws = (float*)d_ws;
        flux_mfma_kernel<<<dim3(NDIR * BLOCKS_PER_DIR), dim3(256), 0, stream>>>(
            q, W0, b0, W1, b1, W2, b2, W3, b3, Wout, bout, ws);
        gather_kernel<<<dim3(NVOX / 256), dim3(256), 0, stream>>>(q, ws, out);
    } else {
        automaton_kernel<<<dim3(NVOX * 2 / 256), dim3(256), 0, stream>>>(
            q, W0, b0, W1, b1, W2, b2, W3, b3, Wout, bout, out);
    }
}